// Round 1
// baseline (1118.867 us; speedup 1.0000x reference)
//
#include <hip/hip_runtime.h>
#include <hip/hip_bf16.h>
#include <cstdint>

#define NB 32
#define NT 2000
#define TP 2048
#define NENC 1024
#define NDEC 1024
#define NATTN 512
#define NHEAD 4
#define NH 2048      // NHEAD*NATTN
#define NC 64
#define NKS 50
#define NKLEN 101
#define NPH 256
#define NPROF 101

typedef __attribute__((ext_vector_type(8))) short bf16x8;
typedef __attribute__((ext_vector_type(4))) float f32x4;
typedef __attribute__((ext_vector_type(8))) unsigned short u16x8;

__device__ __forceinline__ void gload_lds16(const void* g, void* l) {
    __builtin_amdgcn_global_load_lds((__attribute__((address_space(1))) void*)(g),
                                     (__attribute__((address_space(3))) void*)(l), 16, 0, 0);
}

__device__ __forceinline__ unsigned short f2bf(float f) {
    unsigned u = __float_as_uint(f);
    return (unsigned short)((u + 0x7fffu + ((u >> 16) & 1u)) >> 16);
}

__device__ __forceinline__ int prof_of(int t, int len) {
    if (t < NKS) return t;
    if (t < len - NKS) return NKS;
    if (t < len) return NKS + 1 + (t - (len - NKS));
    return NKS;
}

// ---------------- f32 -> bf16 conversion (vectorized 8/thread) ----------------
__global__ void k_convert(const float* __restrict__ src, unsigned short* __restrict__ dst, int n8) {
    int stride = gridDim.x * blockDim.x;
    for (int i = blockIdx.x * blockDim.x + threadIdx.x; i < n8; i += stride) {
        const float4* s = (const float4*)(src) + (size_t)i * 2;
        float4 x = s[0], y = s[1];
        u16x8 o;
        o[0] = f2bf(x.x); o[1] = f2bf(x.y); o[2] = f2bf(x.z); o[3] = f2bf(x.w);
        o[4] = f2bf(y.x); o[5] = f2bf(y.y); o[6] = f2bf(y.z); o[7] = f2bf(y.w);
        *((u16x8*)dst + i) = o;
    }
}

// ---------------- prefix sums of Wconv rows: wcum[hc][0..101] ----------------
__global__ void k_wcum(const float* __restrict__ Wconv, float* __restrict__ wcum) {
    int hc = threadIdx.x;  // 256 rows
    float c = 0.f;
    wcum[hc * 102] = 0.f;
    for (int k = 0; k < NKLEN; ++k) {
        c += Wconv[hc * NKLEN + k];
        wcum[hc * 102 + k + 1] = c;
    }
}

// ---------------- dec_h[h][b][a] = Wdec[h,a,:].dec[b,:] + bdec ----------------
__global__ void k_dech(const float* __restrict__ dec, const float* __restrict__ Wdec,
                       const float* __restrict__ bdec, float* __restrict__ dech) {
    int h = blockIdx.x >> 5, b = blockIdx.x & 31;
    __shared__ float dl[NDEC];
    int tid = threadIdx.x;
    for (int r = 0; r < 4; ++r) dl[tid + r * 256] = dec[b * NDEC + tid + r * 256];
    __syncthreads();
    for (int a2 = 0; a2 < 2; ++a2) {
        int a = tid + a2 * 256;
        const float4* wr = (const float4*)&Wdec[((size_t)(h * NATTN + a)) * NDEC];
        float acc = 0.f;
        for (int e4 = 0; e4 < NDEC / 4; ++e4) {
            float4 w4 = wr[e4];
            acc += w4.x * dl[e4 * 4] + w4.y * dl[e4 * 4 + 1] + w4.z * dl[e4 * 4 + 2] + w4.w * dl[e4 * 4 + 3];
        }
        dech[(h * NB + b) * NATTN + a] = acc + bdec[h * NATTN + a];
    }
}

// ---- add[b][p][n] = dec_h + benc + bloc + Wloc . conv_profile(p) -------------
__global__ void k_addprof(const float* __restrict__ wcum, const float* __restrict__ dech,
                          const float* __restrict__ benc, const float* __restrict__ bloc,
                          const float* __restrict__ Wloc, const int* __restrict__ enc_len,
                          float* __restrict__ addp) {
    int p = blockIdx.x, b = blockIdx.y;
    int len = enc_len[b];
    __shared__ __align__(16) float convp[256];
    int tid = threadIdx.x;
    int kmin, kmax;
    if (p < NKS)       { kmin = NKS - p; kmax = min(NKLEN, len - p + NKS); }
    else if (p == NKS) { kmin = 0;       kmax = NKLEN; }
    else               { kmin = 0;       kmax = 151 - p; }
    if (kmax < kmin) kmax = kmin;
    float invl = 1.f / (float)len;
    convp[tid] = (wcum[tid * 102 + kmax] - wcum[tid * 102 + kmin]) * invl;
    __syncthreads();
    for (int rr = 0; rr < 8; ++rr) {
        int n = tid + rr * 256;
        int h = n >> 9, a = n & 511;
        float s = dech[(h * NB + b) * NATTN + a] + benc[n] + bloc[n];
        const float4* wl = (const float4*)&Wloc[(size_t)n * NC];
        const float4* cp = (const float4*)&convp[h * NC];
        float acc = 0.f;
        for (int c4 = 0; c4 < NC / 4; ++c4) {
            float4 w4 = wl[c4]; float4 cv = cp[c4];
            acc += w4.x * cv.x + w4.y * cv.y + w4.z * cv.z + w4.w * cv.w;
        }
        addp[((size_t)b * NPROF + p) * NH + n] = s + acc;
    }
}

// ---------------- main fused GEMM + tanh + wattn-reduce -> scores -------------
// grid (16 n-chunks, 16 t-tiles, B). 256 thr = 4 waves, 128x128 tile, K=1024.
__global__ __launch_bounds__(256) void k_gemm(
        const unsigned short* __restrict__ encbf, const unsigned short* __restrict__ wencbf,
        const float* __restrict__ addp, const float* __restrict__ wattn,
        const int* __restrict__ enc_len, float* __restrict__ scores) {
    __shared__ __align__(16) unsigned short As[128 * 32];
    __shared__ __align__(16) unsigned short Bs[128 * 32];
    int n0 = blockIdx.x * 128, t0 = blockIdx.y * 128, b = blockIdx.z;
    int len = enc_len[b];
    if (t0 >= len) return;  // fully-masked tile
    int tid = threadIdx.x, lane = tid & 63, w = tid >> 6;
    int wr = w >> 1, wc = w & 1;
    int ro = lane & 15, g4 = lane >> 4;
    f32x4 acc[4][4] = {};
    const unsigned short* Abase = encbf + (size_t)b * NT * NENC;
    // staging geometry: byte off in tile = w*2048 + q*1024 + lane*16
    int srow = (w * 2048 + lane * 16) >> 6;        // + q*16
    int scolb = (lane & 3) * 16;                   // bytes within 64B row
    for (int kk = 0; kk < NENC / 32; ++kk) {
        int k0 = kk * 32;
        for (int q = 0; q < 2; ++q) {
            int row = srow + q * 16;
            int t = t0 + row; if (t > NT - 1) t = NT - 1;
            gload_lds16((const char*)(Abase + (size_t)t * NENC + k0) + scolb,
                        (char*)As + w * 2048 + q * 1024);
            gload_lds16((const char*)(wencbf + (size_t)(n0 + row) * NENC + k0) + scolb,
                        (char*)Bs + w * 2048 + q * 1024);
        }
        __syncthreads();
        bf16x8 af[4], bfr[4];
        const short* Ap = (const short*)As;
        const short* Bp = (const short*)Bs;
#pragma unroll
        for (int m = 0; m < 4; ++m) af[m] = *(const bf16x8*)&Ap[(wr * 64 + m * 16 + ro) * 32 + g4 * 8];
#pragma unroll
        for (int n = 0; n < 4; ++n) bfr[n] = *(const bf16x8*)&Bp[(wc * 64 + n * 16 + ro) * 32 + g4 * 8];
#pragma unroll
        for (int i = 0; i < 4; ++i)
#pragma unroll
            for (int j = 0; j < 4; ++j)
                acc[i][j] = __builtin_amdgcn_mfma_f32_16x16x32_bf16(af[i], bfr[j], acc[i][j], 0, 0, 0);
        __syncthreads();
    }
    // epilogue: tanh(acc+add)*wattn, reduce over 128 n-cols, atomicAdd to scores
    int h = n0 >> 9;
    const float* addb = addp + (size_t)b * NPROF * NH;
    float* sr = scores + ((size_t)(h * NB + b)) * TP;
#pragma unroll
    for (int i = 0; i < 4; ++i) {
#pragma unroll
        for (int r = 0; r < 4; ++r) {
            int t = t0 + wr * 64 + i * 16 + g4 * 4 + r;
            int tc = t < NT ? t : NT - 1;
            const float* arow = addb + (size_t)prof_of(tc, len) * NH;
            float s = 0.f;
#pragma unroll
            for (int j = 0; j < 4; ++j) {
                int n = n0 + wc * 64 + j * 16 + ro;
                float v = acc[i][j][r] + arow[n];
                v = fminf(fmaxf(v, -15.f), 15.f);
                float e2 = __expf(2.f * v);
                s += ((e2 - 1.f) / (e2 + 1.f)) * wattn[n];
            }
            s += __shfl_xor(s, 1); s += __shfl_xor(s, 2);
            s += __shfl_xor(s, 4); s += __shfl_xor(s, 8);
            if (ro == 0 && t < NT) atomicAdd(&sr[t], s);
        }
    }
}

// ---------------- masked softmax over t per (h,b) -> attn ---------------------
__global__ void k_softmax(const float* __restrict__ scores, const int* __restrict__ enc_len,
                          float* __restrict__ attn) {
    int h = blockIdx.x >> 5, b = blockIdx.x & 31;
    int len = enc_len[b];
    int tid = threadIdx.x;
    const float* row = scores + ((size_t)(h * NB + b)) * TP;
    __shared__ float red[4];
    float m = -1e30f;
    for (int t = tid; t < len; t += 256) m = fmaxf(m, row[t]);
    for (int d = 32; d; d >>= 1) m = fmaxf(m, __shfl_xor(m, d));
    if ((tid & 63) == 0) red[tid >> 6] = m;
    __syncthreads();
    m = fmaxf(fmaxf(red[0], red[1]), fmaxf(red[2], red[3]));
    __syncthreads();
    float z = 0.f;
    for (int t = tid; t < len; t += 256) z += __expf(row[t] - m);
    for (int d = 32; d; d >>= 1) z += __shfl_xor(z, d);
    if ((tid & 63) == 0) red[tid >> 6] = z;
    __syncthreads();
    z = red[0] + red[1] + red[2] + red[3];
    float inv = 1.f / z;
    for (int t = tid; t < NT; t += 256) {
        float av = (t < len) ? __expf(row[t] - m) * inv : 0.f;
        attn[((size_t)(h * NB + b)) * NT + t] = av;
    }
}

// ---------------- attn_weight = mean over heads ------------------------------
__global__ void k_attnw(const float* __restrict__ attn, float* __restrict__ out) {
    int b = blockIdx.y;
    int t = blockIdx.x * 256 + threadIdx.x;
    if (t < NT) {
        float s = 0.f;
        for (int h = 0; h < NHEAD; ++h) s += attn[((size_t)(h * NB + b)) * NT + t];
        out[NB * 1024 + b * NT + t] = 0.25f * s;
    }
}

// ---------------- ctx partials: [ts][h][b][e] --------------------------------
__global__ void k_ctx(const float* __restrict__ enc, const float* __restrict__ attn,
                      const int* __restrict__ enc_len, float* __restrict__ ctxp) {
    int ec = blockIdx.x, ts = blockIdx.y, b = blockIdx.z;
    int tid = threadIdx.x;
    __shared__ float attnL[NHEAD][500];
    int t0 = ts * 500;
    for (int i = tid; i < NHEAD * 500; i += 256) {
        int hh = i / 500, tt = i - hh * 500;
        attnL[hh][tt] = attn[((size_t)(hh * NB + b)) * NT + t0 + tt];
    }
    __syncthreads();
    int len = enc_len[b];
    int t1 = min(t0 + 500, len);
    int e = ec * 256 + tid;
    float a0 = 0.f, a1 = 0.f, a2 = 0.f, a3 = 0.f;
    for (int t = t0; t < t1; ++t) {
        float ev = enc[((size_t)b * NT + t) * NENC + e];
        int tt = t - t0;
        a0 += attnL[0][tt] * ev; a1 += attnL[1][tt] * ev;
        a2 += attnL[2][tt] * ev; a3 += attnL[3][tt] * ev;
    }
    ctxp[(((size_t)ts * NHEAD + 0) * NB + b) * NENC + e] = a0;
    ctxp[(((size_t)ts * NHEAD + 1) * NB + b) * NENC + e] = a1;
    ctxp[(((size_t)ts * NHEAD + 2) * NB + b) * NENC + e] = a2;
    ctxp[(((size_t)ts * NHEAD + 3) * NB + b) * NENC + e] = a3;
}

// ---------------- out[h][b][o] = Wout[h,o,:].ctx + bout ----------------------
__global__ void k_out(const float* __restrict__ ctxp, const float* __restrict__ Wout,
                      const float* __restrict__ bout, float* __restrict__ out) {
    int b = blockIdx.x, h = blockIdx.y;
    int tid = threadIdx.x;
    __shared__ float ctxL[NENC];
    for (int r = 0; r < 4; ++r) {
        int e = tid + r * 256;
        float s = 0.f;
        for (int s4 = 0; s4 < 4; ++s4) s += ctxp[(((size_t)s4 * NHEAD + h) * NB + b) * NENC + e];
        ctxL[e] = s;
    }
    __syncthreads();
    int o = tid;
    float acc = bout[h * NPH + o];
    const float4* wrow = (const float4*)&Wout[((size_t)(h * NPH + o)) * NENC];
    for (int e4 = 0; e4 < NENC / 4; ++e4) {
        float4 w4 = wrow[e4];
        acc += w4.x * ctxL[e4 * 4] + w4.y * ctxL[e4 * 4 + 1] + w4.z * ctxL[e4 * 4 + 2] + w4.w * ctxL[e4 * 4 + 3];
    }
    out[b * 1024 + h * NPH + o] = acc;
}

extern "C" void kernel_launch(void* const* d_in, const int* in_sizes, int n_in,
                              void* d_out, int out_size, void* d_ws, size_t ws_size,
                              hipStream_t stream) {
    const float* enc   = (const float*)d_in[0];
    const int*   elen  = (const int*)d_in[1];
    const float* dec   = (const float*)d_in[2];
    const float* Wenc  = (const float*)d_in[3];
    const float* benc  = (const float*)d_in[4];
    const float* Wdec  = (const float*)d_in[5];
    const float* bdec  = (const float*)d_in[6];
    const float* wattn = (const float*)d_in[7];
    const float* Wconv = (const float*)d_in[8];
    const float* Wloc  = (const float*)d_in[9];
    const float* bloc  = (const float*)d_in[10];
    const float* Wout  = (const float*)d_in[11];
    const float* bout  = (const float*)d_in[12];
    float* out = (float*)d_out;

    char* ws = (char*)d_ws;
    size_t off = 0;
    auto alloc = [&](size_t bytes) { size_t o = off; off += (bytes + 255) & ~(size_t)255; return o; };
    unsigned short* encbf  = (unsigned short*)(ws + alloc((size_t)NB * NT * NENC * 2));
    unsigned short* wencbf = (unsigned short*)(ws + alloc((size_t)NH * NENC * 2));
    float* wcum = (float*)(ws + alloc((size_t)256 * 102 * 4));
    float* dech = (float*)(ws + alloc((size_t)NHEAD * NB * NATTN * 4));
    float* addp = (float*)(ws + alloc((size_t)NB * NPROF * NH * 4));
    float* scor = (float*)(ws + alloc((size_t)NHEAD * NB * TP * 4));
    float* attn = (float*)(ws + alloc((size_t)NHEAD * NB * NT * 4));
    float* ctxp = (float*)(ws + alloc((size_t)4 * NHEAD * NB * NENC * 4));
    if (off > ws_size) return;  // insufficient workspace: bail (validation will flag it)

    k_convert<<<2048, 256, 0, stream>>>(enc, encbf, NB * NT * NENC / 8);
    k_convert<<<64, 256, 0, stream>>>(Wenc, wencbf, NH * NENC / 8);
    k_wcum<<<1, 256, 0, stream>>>(Wconv, wcum);
    k_dech<<<NHEAD * NB, 256, 0, stream>>>(dec, Wdec, bdec, dech);
    k_addprof<<<dim3(NPROF, NB), 256, 0, stream>>>(wcum, dech, benc, bloc, Wloc, elen, addp);
    hipMemsetAsync(scor, 0, (size_t)NHEAD * NB * TP * 4, stream);
    k_gemm<<<dim3(16, 16, NB), 256, 0, stream>>>(encbf, wencbf, addp, wattn, elen, scor);
    k_softmax<<<NHEAD * NB, 256, 0, stream>>>(scor, elen, attn);
    k_attnw<<<dim3(8, NB), 256, 0, stream>>>(attn, out);
    k_ctx<<<dim3(4, 4, NB), 256, 0, stream>>>(enc, attn, elen, ctxp);
    k_out<<<dim3(NB, NHEAD), 256, 0, stream>>>(ctxp, Wout, bout, out);
}

// Round 2
// 784.782 us; speedup vs baseline: 1.4257x; 1.4257x over previous
//
#include <hip/hip_runtime.h>
#include <hip/hip_bf16.h>
#include <cstdint>

#define NB 32
#define NT 2000
#define TP 2048
#define NENC 1024
#define NDEC 1024
#define NATTN 512
#define NHEAD 4
#define NH 2048      // NHEAD*NATTN
#define NC 64
#define NKS 50
#define NKLEN 101
#define NPH 256
#define NPROF 101

typedef __attribute__((ext_vector_type(8))) short bf16x8;
typedef __attribute__((ext_vector_type(4))) float f32x4;
typedef __attribute__((ext_vector_type(8))) unsigned short u16x8;

__device__ __forceinline__ void gload_lds16(const void* g, void* l) {
    __builtin_amdgcn_global_load_lds((__attribute__((address_space(1))) void*)(g),
                                     (__attribute__((address_space(3))) void*)(l), 16, 0, 0);
}

__device__ __forceinline__ unsigned short f2bf(float f) {
    unsigned u = __float_as_uint(f);
    return (unsigned short)((u + 0x7fffu + ((u >> 16) & 1u)) >> 16);
}

__device__ __forceinline__ int prof_of(int t, int len) {
    if (t < NKS) return t;
    if (t < len - NKS) return NKS;
    if (t < len) return NKS + 1 + (t - (len - NKS));
    return NKS;
}

__device__ __forceinline__ float4 f4add3(float4 a, float4 b, float4 c) {
    return make_float4(a.x + b.x + c.x, a.y + b.y + c.y, a.z + b.z + c.z, a.w + b.w + c.w);
}
__device__ __forceinline__ float4 f4fma(float s, float4 a, float4 acc) {
    return make_float4(fmaf(s, a.x, acc.x), fmaf(s, a.y, acc.y),
                       fmaf(s, a.z, acc.z), fmaf(s, a.w, acc.w));
}

// ---------------- f32 -> bf16 conversion (vectorized 8/thread) ----------------
__global__ void k_convert(const float* __restrict__ src, unsigned short* __restrict__ dst, int n8) {
    int stride = gridDim.x * blockDim.x;
    for (int i = blockIdx.x * blockDim.x + threadIdx.x; i < n8; i += stride) {
        const float4* s = (const float4*)(src) + (size_t)i * 2;
        float4 x = s[0], y = s[1];
        u16x8 o;
        o[0] = f2bf(x.x); o[1] = f2bf(x.y); o[2] = f2bf(x.z); o[3] = f2bf(x.w);
        o[4] = f2bf(y.x); o[5] = f2bf(y.y); o[6] = f2bf(y.z); o[7] = f2bf(y.w);
        *((u16x8*)dst + i) = o;
    }
}

// ---------------- prefix sums of Wconv rows: wcum[hc][0..101] ----------------
__global__ void k_wcum(const float* __restrict__ Wconv, float* __restrict__ wcum) {
    int hc = threadIdx.x;  // 256 rows
    float c = 0.f;
    wcum[hc * 102] = 0.f;
    for (int k = 0; k < NKLEN; ++k) {
        c += Wconv[hc * NKLEN + k];
        wcum[hc * 102 + k + 1] = c;
    }
}

// ---------------- WlocT[c][n] = Wloc[n][c] (512 KB, one-shot) ----------------
__global__ void k_wlocT(const float* __restrict__ Wloc, float* __restrict__ wlocT) {
    int c = blockIdx.x;  // 64
    for (int n = threadIdx.x; n < NH; n += 256)
        wlocT[c * NH + n] = Wloc[(size_t)n * NC + c];
}

// ---------------- dec_h[h][b][a] = Wdec[h,a,:].dec[b,:] + bdec ----------------
__global__ void k_dech(const float* __restrict__ dec, const float* __restrict__ Wdec,
                       const float* __restrict__ bdec, float* __restrict__ dech) {
    int h = blockIdx.x >> 5, b = blockIdx.x & 31;
    __shared__ float dl[NDEC];
    int tid = threadIdx.x;
    for (int r = 0; r < 4; ++r) dl[tid + r * 256] = dec[b * NDEC + tid + r * 256];
    __syncthreads();
    for (int a2 = 0; a2 < 2; ++a2) {
        int a = tid + a2 * 256;
        const float4* wr = (const float4*)&Wdec[((size_t)(h * NATTN + a)) * NDEC];
        float acc = 0.f;
        for (int e4 = 0; e4 < NDEC / 4; ++e4) {
            float4 w4 = wr[e4];
            acc += w4.x * dl[e4 * 4] + w4.y * dl[e4 * 4 + 1] + w4.z * dl[e4 * 4 + 2] + w4.w * dl[e4 * 4 + 3];
        }
        dech[(h * NB + b) * NATTN + a] = acc + bdec[h * NATTN + a];
    }
}

// ---- add[b][p][n] = dec_h + benc + bloc + WlocT^T . conv_profile(p) ----------
// Coalesced: threads map to consecutive n (float4/lane); 4 profiles per block
// amortize the WlocT sweep. conv scalars broadcast from LDS.
__global__ void k_addprof(const float* __restrict__ wcum, const float* __restrict__ dech,
                          const float* __restrict__ benc, const float* __restrict__ bloc,
                          const float* __restrict__ wlocT, const int* __restrict__ enc_len,
                          float* __restrict__ addp) {
    int p0 = blockIdx.x * 4, b = blockIdx.y;
    int len = enc_len[b];
    __shared__ float convp[4][256];
    int tid = threadIdx.x;
    float invl = 1.f / (float)len;
#pragma unroll
    for (int pp = 0; pp < 4; ++pp) {
        int p = min(p0 + pp, NPROF - 1);
        int kmin, kmax;
        if (p < NKS)       { kmin = NKS - p; kmax = min(NKLEN, len - p + NKS); }
        else if (p == NKS) { kmin = 0;       kmax = NKLEN; }
        else               { kmin = 0;       kmax = 151 - p; }
        if (kmax < kmin) kmax = kmin;
        convp[pp][tid] = (wcum[tid * 102 + kmax] - wcum[tid * 102 + kmin]) * invl;
    }
    __syncthreads();
    int h0 = tid >> 7, h1 = 2 + h0;
    int n40 = tid, n41 = 256 + tid;   // float4 indices into the 2048-wide n dim
    const float4* dech4 = (const float4*)dech;
    const float4* benc4 = (const float4*)benc;
    const float4* bloc4 = (const float4*)bloc;
    float4 base0 = f4add3(dech4[(h0 * NB + b) * 128 + (tid & 127)], benc4[n40], bloc4[n40]);
    float4 base1 = f4add3(dech4[(h1 * NB + b) * 128 + (tid & 127)], benc4[n41], bloc4[n41]);
    float4 acc[4][2];
#pragma unroll
    for (int pp = 0; pp < 4; ++pp) { acc[pp][0] = base0; acc[pp][1] = base1; }
    const float4* wT4 = (const float4*)wlocT;
#pragma unroll 4
    for (int c = 0; c < NC; ++c) {
        float4 w0 = wT4[c * 512 + n40];
        float4 w1 = wT4[c * 512 + n41];
#pragma unroll
        for (int pp = 0; pp < 4; ++pp) {
            acc[pp][0] = f4fma(convp[pp][h0 * 64 + c], w0, acc[pp][0]);
            acc[pp][1] = f4fma(convp[pp][h1 * 64 + c], w1, acc[pp][1]);
        }
    }
    float4* addp4 = (float4*)addp;
#pragma unroll
    for (int pp = 0; pp < 4; ++pp) {
        int p = p0 + pp;
        if (p < NPROF) {
            addp4[((size_t)(b * NPROF + p)) * 512 + n40] = acc[pp][0];
            addp4[((size_t)(b * NPROF + p)) * 512 + n41] = acc[pp][1];
        }
    }
}

// ---------------- main fused GEMM + tanh + wattn-reduce -> scores -------------
// grid (16 n-chunks, 16 t-tiles, B). 256 thr = 4 waves, 128x128 tile, K=1024.
__global__ __launch_bounds__(256) void k_gemm(
        const unsigned short* __restrict__ encbf, const unsigned short* __restrict__ wencbf,
        const float* __restrict__ addp, const float* __restrict__ wattn,
        const int* __restrict__ enc_len, float* __restrict__ scores) {
    __shared__ __align__(16) unsigned short As[128 * 32];
    __shared__ __align__(16) unsigned short Bs[128 * 32];
    int n0 = blockIdx.x * 128, t0 = blockIdx.y * 128, b = blockIdx.z;
    int len = enc_len[b];
    if (t0 >= len) return;  // fully-masked tile
    int tid = threadIdx.x, lane = tid & 63, w = tid >> 6;
    int wr = w >> 1, wc = w & 1;
    int ro = lane & 15, g4 = lane >> 4;
    f32x4 acc[4][4] = {};
    const unsigned short* Abase = encbf + (size_t)b * NT * NENC;
    // staging geometry: byte off in tile = w*2048 + q*1024 + lane*16
    int srow = (w * 2048 + lane * 16) >> 6;        // + q*16
    int scolb = (lane & 3) * 16;                   // bytes within 64B row
    for (int kk = 0; kk < NENC / 32; ++kk) {
        int k0 = kk * 32;
        for (int q = 0; q < 2; ++q) {
            int row = srow + q * 16;
            int t = t0 + row; if (t > NT - 1) t = NT - 1;
            gload_lds16((const char*)(Abase + (size_t)t * NENC + k0) + scolb,
                        (char*)As + w * 2048 + q * 1024);
            gload_lds16((const char*)(wencbf + (size_t)(n0 + row) * NENC + k0) + scolb,
                        (char*)Bs + w * 2048 + q * 1024);
        }
        __syncthreads();
        bf16x8 af[4], bfr[4];
        const short* Ap = (const short*)As;
        const short* Bp = (const short*)Bs;
#pragma unroll
        for (int m = 0; m < 4; ++m) af[m] = *(const bf16x8*)&Ap[(wr * 64 + m * 16 + ro) * 32 + g4 * 8];
#pragma unroll
        for (int n = 0; n < 4; ++n) bfr[n] = *(const bf16x8*)&Bp[(wc * 64 + n * 16 + ro) * 32 + g4 * 8];
#pragma unroll
        for (int i = 0; i < 4; ++i)
#pragma unroll
            for (int j = 0; j < 4; ++j)
                acc[i][j] = __builtin_amdgcn_mfma_f32_16x16x32_bf16(af[i], bfr[j], acc[i][j], 0, 0, 0);
        __syncthreads();
    }
    // epilogue: tanh(acc+add)*wattn, reduce over 128 n-cols, atomicAdd to scores
    int h = n0 >> 9;
    const float* addb = addp + (size_t)b * NPROF * NH;
    float* sr = scores + ((size_t)(h * NB + b)) * TP;
#pragma unroll
    for (int i = 0; i < 4; ++i) {
#pragma unroll
        for (int r = 0; r < 4; ++r) {
            int t = t0 + wr * 64 + i * 16 + g4 * 4 + r;
            int tc = t < NT ? t : NT - 1;
            const float* arow = addb + (size_t)prof_of(tc, len) * NH;
            float s = 0.f;
#pragma unroll
            for (int j = 0; j < 4; ++j) {
                int n = n0 + wc * 64 + j * 16 + ro;
                float v = acc[i][j][r] + arow[n];
                v = fminf(fmaxf(v, -15.f), 15.f);
                float e2 = __expf(2.f * v);
                s += ((e2 - 1.f) / (e2 + 1.f)) * wattn[n];
            }
            s += __shfl_xor(s, 1); s += __shfl_xor(s, 2);
            s += __shfl_xor(s, 4); s += __shfl_xor(s, 8);
            if (ro == 0 && t < NT) atomicAdd(&sr[t], s);
        }
    }
}

// ---------------- masked softmax over t per (h,b) -> attn ---------------------
__global__ void k_softmax(const float* __restrict__ scores, const int* __restrict__ enc_len,
                          float* __restrict__ attn) {
    int h = blockIdx.x >> 5, b = blockIdx.x & 31;
    int len = enc_len[b];
    int tid = threadIdx.x;
    const float* row = scores + ((size_t)(h * NB + b)) * TP;
    __shared__ float red[4];
    float m = -1e30f;
    for (int t = tid; t < len; t += 256) m = fmaxf(m, row[t]);
    for (int d = 32; d; d >>= 1) m = fmaxf(m, __shfl_xor(m, d));
    if ((tid & 63) == 0) red[tid >> 6] = m;
    __syncthreads();
    m = fmaxf(fmaxf(red[0], red[1]), fmaxf(red[2], red[3]));
    __syncthreads();
    float z = 0.f;
    for (int t = tid; t < len; t += 256) z += __expf(row[t] - m);
    for (int d = 32; d; d >>= 1) z += __shfl_xor(z, d);
    if ((tid & 63) == 0) red[tid >> 6] = z;
    __syncthreads();
    z = red[0] + red[1] + red[2] + red[3];
    float inv = 1.f / z;
    for (int t = tid; t < NT; t += 256) {
        float av = (t < len) ? __expf(row[t] - m) * inv : 0.f;
        attn[((size_t)(h * NB + b)) * NT + t] = av;
    }
}

// ---------------- attn_weight = mean over heads ------------------------------
__global__ void k_attnw(const float* __restrict__ attn, float* __restrict__ out) {
    int b = blockIdx.y;
    int t = blockIdx.x * 256 + threadIdx.x;
    if (t < NT) {
        float s = 0.f;
        for (int h = 0; h < NHEAD; ++h) s += attn[((size_t)(h * NB + b)) * NT + t];
        out[NB * 1024 + b * NT + t] = 0.25f * s;
    }
}

// ---------------- ctx partials: [ts][h][b][e] --------------------------------
__global__ void k_ctx(const float* __restrict__ enc, const float* __restrict__ attn,
                      const int* __restrict__ enc_len, float* __restrict__ ctxp) {
    int ec = blockIdx.x, ts = blockIdx.y, b = blockIdx.z;
    int tid = threadIdx.x;
    __shared__ float attnL[NHEAD][500];
    int t0 = ts * 500;
    for (int i = tid; i < NHEAD * 500; i += 256) {
        int hh = i / 500, tt = i - hh * 500;
        attnL[hh][tt] = attn[((size_t)(hh * NB + b)) * NT + t0 + tt];
    }
    __syncthreads();
    int len = enc_len[b];
    int t1 = min(t0 + 500, len);
    int e = ec * 256 + tid;
    float a0 = 0.f, a1 = 0.f, a2 = 0.f, a3 = 0.f;
    for (int t = t0; t < t1; ++t) {
        float ev = enc[((size_t)b * NT + t) * NENC + e];
        int tt = t - t0;
        a0 += attnL[0][tt] * ev; a1 += attnL[1][tt] * ev;
        a2 += attnL[2][tt] * ev; a3 += attnL[3][tt] * ev;
    }
    ctxp[(((size_t)ts * NHEAD + 0) * NB + b) * NENC + e] = a0;
    ctxp[(((size_t)ts * NHEAD + 1) * NB + b) * NENC + e] = a1;
    ctxp[(((size_t)ts * NHEAD + 2) * NB + b) * NENC + e] = a2;
    ctxp[(((size_t)ts * NHEAD + 3) * NB + b) * NENC + e] = a3;
}

// ---------------- out[h][b][o] = Wout[h,o,:].ctx + bout ----------------------
__global__ void k_out(const float* __restrict__ ctxp, const float* __restrict__ Wout,
                      const float* __restrict__ bout, float* __restrict__ out) {
    int b = blockIdx.x, h = blockIdx.y;
    int tid = threadIdx.x;
    __shared__ float ctxL[NENC];
    for (int r = 0; r < 4; ++r) {
        int e = tid + r * 256;
        float s = 0.f;
        for (int s4 = 0; s4 < 4; ++s4) s += ctxp[(((size_t)s4 * NHEAD + h) * NB + b) * NENC + e];
        ctxL[e] = s;
    }
    __syncthreads();
    int o = tid;
    float acc = bout[h * NPH + o];
    const float4* wrow = (const float4*)&Wout[((size_t)(h * NPH + o)) * NENC];
    for (int e4 = 0; e4 < NENC / 4; ++e4) {
        float4 w4 = wrow[e4];
        acc += w4.x * ctxL[e4 * 4] + w4.y * ctxL[e4 * 4 + 1] + w4.z * ctxL[e4 * 4 + 2] + w4.w * ctxL[e4 * 4 + 3];
    }
    out[b * 1024 + h * NPH + o] = acc;
}

extern "C" void kernel_launch(void* const* d_in, const int* in_sizes, int n_in,
                              void* d_out, int out_size, void* d_ws, size_t ws_size,
                              hipStream_t stream) {
    const float* enc   = (const float*)d_in[0];
    const int*   elen  = (const int*)d_in[1];
    const float* dec   = (const float*)d_in[2];
    const float* Wenc  = (const float*)d_in[3];
    const float* benc  = (const float*)d_in[4];
    const float* Wdec  = (const float*)d_in[5];
    const float* bdec  = (const float*)d_in[6];
    const float* wattn = (const float*)d_in[7];
    const float* Wconv = (const float*)d_in[8];
    const float* Wloc  = (const float*)d_in[9];
    const float* bloc  = (const float*)d_in[10];
    const float* Wout  = (const float*)d_in[11];
    const float* bout  = (const float*)d_in[12];
    float* out = (float*)d_out;

    char* ws = (char*)d_ws;
    size_t off = 0;
    auto alloc = [&](size_t bytes) { size_t o = off; off += (bytes + 255) & ~(size_t)255; return o; };
    unsigned short* encbf  = (unsigned short*)(ws + alloc((size_t)NB * NT * NENC * 2));
    unsigned short* wencbf = (unsigned short*)(ws + alloc((size_t)NH * NENC * 2));
    float* wcum  = (float*)(ws + alloc((size_t)256 * 102 * 4));
    float* wlocT = (float*)(ws + alloc((size_t)NC * NH * 4));
    float* dech  = (float*)(ws + alloc((size_t)NHEAD * NB * NATTN * 4));
    float* addp  = (float*)(ws + alloc((size_t)NB * NPROF * NH * 4));
    float* scor  = (float*)(ws + alloc((size_t)NHEAD * NB * TP * 4));
    float* attn  = (float*)(ws + alloc((size_t)NHEAD * NB * NT * 4));
    float* ctxp  = (float*)(ws + alloc((size_t)4 * NHEAD * NB * NENC * 4));
    if (off > ws_size) return;  // insufficient workspace: bail (validation will flag it)

    k_convert<<<2048, 256, 0, stream>>>(enc, encbf, NB * NT * NENC / 8);
    k_convert<<<64, 256, 0, stream>>>(Wenc, wencbf, NH * NENC / 8);
    k_wcum<<<1, 256, 0, stream>>>(Wconv, wcum);
    k_wlocT<<<64, 256, 0, stream>>>(Wloc, wlocT);
    k_dech<<<NHEAD * NB, 256, 0, stream>>>(dec, Wdec, bdec, dech);
    k_addprof<<<dim3((NPROF + 3) / 4, NB), 256, 0, stream>>>(wcum, dech, benc, bloc, wlocT, elen, addp);
    hipMemsetAsync(scor, 0, (size_t)NHEAD * NB * TP * 4, stream);
    k_gemm<<<dim3(16, 16, NB), 256, 0, stream>>>(encbf, wencbf, addp, wattn, elen, scor);
    k_softmax<<<NHEAD * NB, 256, 0, stream>>>(scor, elen, attn);
    k_attnw<<<dim3(8, NB), 256, 0, stream>>>(attn, out);
    k_ctx<<<dim3(4, 4, NB), 256, 0, stream>>>(enc, attn, elen, ctxp);
    k_out<<<dim3(NB, NHEAD), 256, 0, stream>>>(ctxp, Wout, bout, out);
}

// Round 3
// 781.859 us; speedup vs baseline: 1.4310x; 1.0037x over previous
//
#include <hip/hip_runtime.h>
#include <hip/hip_bf16.h>
#include <cstdint>

#define NB 32
#define NT 2000
#define TP 2048
#define NENC 1024
#define NDEC 1024
#define NATTN 512
#define NHEAD 4
#define NH 2048      // NHEAD*NATTN
#define NC 64
#define NKS 50
#define NKLEN 101
#define NPH 256
#define NPROF 101
#define NKT 32       // K tiles of 32 in the main GEMM

typedef __attribute__((ext_vector_type(8))) short bf16x8;
typedef __attribute__((ext_vector_type(4))) float f32x4;
typedef __attribute__((ext_vector_type(8))) unsigned short u16x8;

__device__ __forceinline__ void gload_lds16(const void* g, void* l) {
    __builtin_amdgcn_global_load_lds((__attribute__((address_space(1))) void*)(g),
                                     (__attribute__((address_space(3))) void*)(l), 16, 0, 0);
}

__device__ __forceinline__ unsigned short f2bf(float f) {
    unsigned u = __float_as_uint(f);
    return (unsigned short)((u + 0x7fffu + ((u >> 16) & 1u)) >> 16);
}

__device__ __forceinline__ int prof_of(int t, int len) {
    if (t < NKS) return t;
    if (t < len - NKS) return NKS;
    if (t < len) return NKS + 1 + (t - (len - NKS));
    return NKS;
}

__device__ __forceinline__ float4 f4add3(float4 a, float4 b, float4 c) {
    return make_float4(a.x + b.x + c.x, a.y + b.y + c.y, a.z + b.z + c.z, a.w + b.w + c.w);
}
__device__ __forceinline__ float4 f4fma(float s, float4 a, float4 acc) {
    return make_float4(fmaf(s, a.x, acc.x), fmaf(s, a.y, acc.y),
                       fmaf(s, a.z, acc.z), fmaf(s, a.w, acc.w));
}

// ---------------- f32 -> bf16 conversion (vectorized 8/thread) ----------------
__global__ void k_convert(const float* __restrict__ src, unsigned short* __restrict__ dst, int n8) {
    int stride = gridDim.x * blockDim.x;
    for (int i = blockIdx.x * blockDim.x + threadIdx.x; i < n8; i += stride) {
        const float4* s = (const float4*)(src) + (size_t)i * 2;
        float4 x = s[0], y = s[1];
        u16x8 o;
        o[0] = f2bf(x.x); o[1] = f2bf(x.y); o[2] = f2bf(x.z); o[3] = f2bf(x.w);
        o[4] = f2bf(y.x); o[5] = f2bf(y.y); o[6] = f2bf(y.z); o[7] = f2bf(y.w);
        *((u16x8*)dst + i) = o;
    }
}

// ---------------- prefix sums of Wconv rows: wcum[hc][0..101] ----------------
__global__ void k_wcum(const float* __restrict__ Wconv, float* __restrict__ wcum) {
    int hc = threadIdx.x;  // 256 rows
    float c = 0.f;
    wcum[hc * 102] = 0.f;
    for (int k = 0; k < NKLEN; ++k) {
        c += Wconv[hc * NKLEN + k];
        wcum[hc * 102 + k + 1] = c;
    }
}

// ---------------- WlocT[c][n] = Wloc[n][c] (512 KB, one-shot) ----------------
__global__ void k_wlocT(const float* __restrict__ Wloc, float* __restrict__ wlocT) {
    int c = blockIdx.x;  // 64
    for (int n = threadIdx.x; n < NH; n += 256)
        wlocT[c * NH + n] = Wloc[(size_t)n * NC + c];
}

// ---------------- dec_h[h][b][a] = Wdec[h,a,:].dec[b,:] + bdec ----------------
__global__ void k_dech(const float* __restrict__ dec, const float* __restrict__ Wdec,
                       const float* __restrict__ bdec, float* __restrict__ dech) {
    int h = blockIdx.x >> 5, b = blockIdx.x & 31;
    __shared__ float dl[NDEC];
    int tid = threadIdx.x;
    for (int r = 0; r < 4; ++r) dl[tid + r * 256] = dec[b * NDEC + tid + r * 256];
    __syncthreads();
    for (int a2 = 0; a2 < 2; ++a2) {
        int a = tid + a2 * 256;
        const float4* wr = (const float4*)&Wdec[((size_t)(h * NATTN + a)) * NDEC];
        float acc = 0.f;
        for (int e4 = 0; e4 < NDEC / 4; ++e4) {
            float4 w4 = wr[e4];
            acc += w4.x * dl[e4 * 4] + w4.y * dl[e4 * 4 + 1] + w4.z * dl[e4 * 4 + 2] + w4.w * dl[e4 * 4 + 3];
        }
        dech[(h * NB + b) * NATTN + a] = acc + bdec[h * NATTN + a];
    }
}

// ---- add[b][p][n] = dec_h + benc + bloc + WlocT^T . conv_profile(p) ----------
__global__ void k_addprof(const float* __restrict__ wcum, const float* __restrict__ dech,
                          const float* __restrict__ benc, const float* __restrict__ bloc,
                          const float* __restrict__ wlocT, const int* __restrict__ enc_len,
                          float* __restrict__ addp) {
    int p0 = blockIdx.x * 4, b = blockIdx.y;
    int len = enc_len[b];
    __shared__ float convp[4][256];
    int tid = threadIdx.x;
    float invl = 1.f / (float)len;
#pragma unroll
    for (int pp = 0; pp < 4; ++pp) {
        int p = min(p0 + pp, NPROF - 1);
        int kmin, kmax;
        if (p < NKS)       { kmin = NKS - p; kmax = min(NKLEN, len - p + NKS); }
        else if (p == NKS) { kmin = 0;       kmax = NKLEN; }
        else               { kmin = 0;       kmax = 151 - p; }
        if (kmax < kmin) kmax = kmin;
        convp[pp][tid] = (wcum[tid * 102 + kmax] - wcum[tid * 102 + kmin]) * invl;
    }
    __syncthreads();
    int h0 = tid >> 7, h1 = 2 + h0;
    int n40 = tid, n41 = 256 + tid;   // float4 indices into the 2048-wide n dim
    const float4* dech4 = (const float4*)dech;
    const float4* benc4 = (const float4*)benc;
    const float4* bloc4 = (const float4*)bloc;
    float4 base0 = f4add3(dech4[(h0 * NB + b) * 128 + (tid & 127)], benc4[n40], bloc4[n40]);
    float4 base1 = f4add3(dech4[(h1 * NB + b) * 128 + (tid & 127)], benc4[n41], bloc4[n41]);
    float4 acc[4][2];
#pragma unroll
    for (int pp = 0; pp < 4; ++pp) { acc[pp][0] = base0; acc[pp][1] = base1; }
    const float4* wT4 = (const float4*)wlocT;
#pragma unroll 4
    for (int c = 0; c < NC; ++c) {
        float4 w0 = wT4[c * 512 + n40];
        float4 w1 = wT4[c * 512 + n41];
#pragma unroll
        for (int pp = 0; pp < 4; ++pp) {
            acc[pp][0] = f4fma(convp[pp][h0 * 64 + c], w0, acc[pp][0]);
            acc[pp][1] = f4fma(convp[pp][h1 * 64 + c], w1, acc[pp][1]);
        }
    }
    float4* addp4 = (float4*)addp;
#pragma unroll
    for (int pp = 0; pp < 4; ++pp) {
        int p = p0 + pp;
        if (p < NPROF) {
            addp4[((size_t)(b * NPROF + p)) * 512 + n40] = acc[pp][0];
            addp4[((size_t)(b * NPROF + p)) * 512 + n41] = acc[pp][1];
        }
    }
}

// ---------------- main fused GEMM + tanh + wattn-reduce -> scores -------------
// 256x256 tile, BK=32, 8 waves (2x4), 4-deep LDS ring, counted-vmcnt pipeline.
// LDS ring buffer q (q=kt&3): [A 16KB][B 16KB] at q*32768. A/B tiles are
// [256 rows][32 k] bf16 with chunk-XOR swizzle c ^= (row>>1)&3 (16B chunks),
// applied via pre-swizzled GLOBAL source (linear global_load_lds dest).
__global__ __launch_bounds__(512, 2) void k_gemm(
        const unsigned short* __restrict__ encbf, const unsigned short* __restrict__ wencbf,
        const float* __restrict__ addp, const float* __restrict__ wattn,
        const int* __restrict__ enc_len, float* __restrict__ scores) {
    extern __shared__ char smem[];
    int bid = blockIdx.x;
    int L = (bid & 7) * 256 + (bid >> 3);   // bijective XCD-chunk swizzle (2048%8==0)
    int bx = L & 7, by = (L >> 3) & 7, b = L >> 6;
    int n0 = bx * 256, t0 = by * 256;
    int len = enc_len[b];
    if (t0 >= len) return;  // fully-masked tile
    int tid = threadIdx.x, lane = tid & 63, w = tid >> 6;
    int wr = w >> 2, wc = w & 3;
    int ro = lane & 15, g4 = lane >> 4;

    // staging geometry: wave w stages rows w*32..w*32+31 (2 gloads of 1KB)
    int srow = w * 32 + (lane >> 2);
    int csrc = ((lane & 3) ^ ((lane >> 3) & 3)) * 8;  // pre-swizzled k-chunk (elements)
    const unsigned short* Asrc0 = encbf + (size_t)b * NT * NENC + (size_t)(t0 + srow) * NENC + csrc;
    const unsigned short* Bsrc0 = wencbf + (size_t)(n0 + srow) * NENC + csrc;
    char* dA = smem + w * 2048;
    char* dB = smem + 16384 + w * 2048;

    auto STAGE_A = [&](int kt) {
        char* d = dA + ((kt & 3) << 15);
        const unsigned short* s = Asrc0 + kt * 32;
        gload_lds16(s, d);
        gload_lds16(s + 16 * NENC, d + 1024);
    };
    auto STAGE_B = [&](int kt) {
        char* d = dB + ((kt & 3) << 15);
        const unsigned short* s = Bsrc0 + kt * 32;
        gload_lds16(s, d);
        gload_lds16(s + 16 * NENC, d + 1024);
    };

    f32x4 acc[8][4] = {};
    bf16x8 aR[8];
    int swb = (g4 ^ ((ro >> 1) & 3)) * 16;               // swizzled chunk byte on read
    int rdA = (wr * 128 + ro) * 64 + swb;                 // + m*1024 + q*32768
    int rdB = 16384 + (wc * 64 + ro) * 64 + swb;          // + n*1024 + q*32768

    STAGE_A(0); STAGE_B(0); STAGE_A(1); STAGE_B(1); STAGE_A(2); STAGE_B(2);

#define BAR asm volatile("s_barrier" ::: "memory")
#define PH0(KT, ST, VM) \
    { if (ST) STAGE_A((KT) + 3); \
      asm volatile("s_waitcnt vmcnt(" #VM ")" ::: "memory"); \
      BAR; \
      const char* Aq = smem + (((KT) & 3) << 15); \
      _Pragma("unroll") \
      for (int m = 0; m < 8; ++m) aR[m] = *(const bf16x8*)(Aq + rdA + m * 1024); \
      bf16x8 b0 = *(const bf16x8*)(Aq + rdB); \
      bf16x8 b1 = *(const bf16x8*)(Aq + rdB + 1024); \
      __builtin_amdgcn_s_setprio(1); \
      _Pragma("unroll") \
      for (int m = 0; m < 8; ++m) { \
          acc[m][0] = __builtin_amdgcn_mfma_f32_16x16x32_bf16(aR[m], b0, acc[m][0], 0, 0, 0); \
          acc[m][1] = __builtin_amdgcn_mfma_f32_16x16x32_bf16(aR[m], b1, acc[m][1], 0, 0, 0); } \
      __builtin_amdgcn_s_setprio(0); \
      BAR; }
#define PH1(KT, ST) \
    { if (ST) STAGE_B((KT) + 3); \
      BAR; \
      const char* Aq = smem + (((KT) & 3) << 15); \
      bf16x8 b2 = *(const bf16x8*)(Aq + rdB + 2048); \
      bf16x8 b3 = *(const bf16x8*)(Aq + rdB + 3072); \
      __builtin_amdgcn_s_setprio(1); \
      _Pragma("unroll") \
      for (int m = 0; m < 8; ++m) { \
          acc[m][2] = __builtin_amdgcn_mfma_f32_16x16x32_bf16(aR[m], b2, acc[m][2], 0, 0, 0); \
          acc[m][3] = __builtin_amdgcn_mfma_f32_16x16x32_bf16(aR[m], b3, acc[m][3], 0, 0, 0); } \
      __builtin_amdgcn_s_setprio(0); \
      BAR; }

#pragma unroll 1
    for (int kt = 0; kt < NKT - 3; ++kt) {
        PH0(kt, 1, 10)
        PH1(kt, 1)
    }
    PH0(NKT - 3, 0, 8) PH1(NKT - 3, 0)
    PH0(NKT - 2, 0, 4) PH1(NKT - 2, 0)
    PH0(NKT - 1, 0, 0) PH1(NKT - 1, 0)
#undef PH0
#undef PH1
#undef BAR

    __builtin_amdgcn_sched_barrier(0);
    // epilogue: tanh(acc+add)*wattn, 16-lane reduce over n, atomicAdd to scores
    int h = n0 >> 9;
    float wat[4];
#pragma unroll
    for (int n = 0; n < 4; ++n) wat[n] = wattn[n0 + wc * 64 + n * 16 + ro];
    const float* addb = addp + (size_t)b * NPROF * NH + n0 + wc * 64 + ro;
    float* sr = scores + ((size_t)(h * NB + b)) * TP;
#pragma unroll
    for (int m = 0; m < 8; ++m) {
#pragma unroll
        for (int e = 0; e < 4; ++e) {
            int t = t0 + wr * 128 + m * 16 + g4 * 4 + e;
            int tc = t < NT ? t : NT - 1;
            const float* arow = addb + (size_t)prof_of(tc, len) * NH;
            float s = 0.f;
#pragma unroll
            for (int n = 0; n < 4; ++n) {
                float v = acc[m][n][e] + arow[n * 16];
                v = fminf(fmaxf(v, -15.f), 15.f);
                float e2 = __expf(2.f * v);
                s += ((e2 - 1.f) / (e2 + 1.f)) * wat[n];
            }
            s += __shfl_xor(s, 1); s += __shfl_xor(s, 2);
            s += __shfl_xor(s, 4); s += __shfl_xor(s, 8);
            if (ro == 0) atomicAdd(&sr[t], s);
        }
    }
}

// ---------------- masked softmax over t per (h,b) -> attn ---------------------
__global__ void k_softmax(const float* __restrict__ scores, const int* __restrict__ enc_len,
                          float* __restrict__ attn) {
    int h = blockIdx.x >> 5, b = blockIdx.x & 31;
    int len = enc_len[b];
    int tid = threadIdx.x;
    const float* row = scores + ((size_t)(h * NB + b)) * TP;
    __shared__ float red[4];
    float m = -1e30f;
    for (int t = tid; t < len; t += 256) m = fmaxf(m, row[t]);
    for (int d = 32; d; d >>= 1) m = fmaxf(m, __shfl_xor(m, d));
    if ((tid & 63) == 0) red[tid >> 6] = m;
    __syncthreads();
    m = fmaxf(fmaxf(red[0], red[1]), fmaxf(red[2], red[3]));
    __syncthreads();
    float z = 0.f;
    for (int t = tid; t < len; t += 256) z += __expf(row[t] - m);
    for (int d = 32; d; d >>= 1) z += __shfl_xor(z, d);
    if ((tid & 63) == 0) red[tid >> 6] = z;
    __syncthreads();
    z = red[0] + red[1] + red[2] + red[3];
    float inv = 1.f / z;
    for (int t = tid; t < NT; t += 256) {
        float av = (t < len) ? __expf(row[t] - m) * inv : 0.f;
        attn[((size_t)(h * NB + b)) * NT + t] = av;
    }
}

// ---------------- attn_weight = mean over heads ------------------------------
__global__ void k_attnw(const float* __restrict__ attn, float* __restrict__ out) {
    int b = blockIdx.y;
    int t = blockIdx.x * 256 + threadIdx.x;
    if (t < NT) {
        float s = 0.f;
        for (int h = 0; h < NHEAD; ++h) s += attn[((size_t)(h * NB + b)) * NT + t];
        out[NB * 1024 + b * NT + t] = 0.25f * s;
    }
}

// ---------------- ctx partials: [ts][h][b][e] --------------------------------
__global__ void k_ctx(const float* __restrict__ enc, const float* __restrict__ attn,
                      const int* __restrict__ enc_len, float* __restrict__ ctxp) {
    int ec = blockIdx.x, ts = blockIdx.y, b = blockIdx.z;
    int tid = threadIdx.x;
    __shared__ float attnL[NHEAD][500];
    int t0 = ts * 500;
    for (int i = tid; i < NHEAD * 500; i += 256) {
        int hh = i / 500, tt = i - hh * 500;
        attnL[hh][tt] = attn[((size_t)(hh * NB + b)) * NT + t0 + tt];
    }
    __syncthreads();
    int len = enc_len[b];
    int t1 = min(t0 + 500, len);
    int e = ec * 256 + tid;
    float a0 = 0.f, a1 = 0.f, a2 = 0.f, a3 = 0.f;
    for (int t = t0; t < t1; ++t) {
        float ev = enc[((size_t)b * NT + t) * NENC + e];
        int tt = t - t0;
        a0 += attnL[0][tt] * ev; a1 += attnL[1][tt] * ev;
        a2 += attnL[2][tt] * ev; a3 += attnL[3][tt] * ev;
    }
    ctxp[(((size_t)ts * NHEAD + 0) * NB + b) * NENC + e] = a0;
    ctxp[(((size_t)ts * NHEAD + 1) * NB + b) * NENC + e] = a1;
    ctxp[(((size_t)ts * NHEAD + 2) * NB + b) * NENC + e] = a2;
    ctxp[(((size_t)ts * NHEAD + 3) * NB + b) * NENC + e] = a3;
}

// ---------------- out[h][b][o] = Wout[h,o,:].ctx + bout ----------------------
__global__ void k_out(const float* __restrict__ ctxp, const float* __restrict__ Wout,
                      const float* __restrict__ bout, float* __restrict__ out) {
    int b = blockIdx.x, h = blockIdx.y;
    int tid = threadIdx.x;
    __shared__ float ctxL[NENC];
    for (int r = 0; r < 4; ++r) {
        int e = tid + r * 256;
        float s = 0.f;
        for (int s4 = 0; s4 < 4; ++s4) s += ctxp[(((size_t)s4 * NHEAD + h) * NB + b) * NENC + e];
        ctxL[e] = s;
    }
    __syncthreads();
    int o = tid;
    float acc = bout[h * NPH + o];
    const float4* wrow = (const float4*)&Wout[((size_t)(h * NPH + o)) * NENC];
    for (int e4 = 0; e4 < NENC / 4; ++e4) {
        float4 w4 = wrow[e4];
        acc += w4.x * ctxL[e4 * 4] + w4.y * ctxL[e4 * 4 + 1] + w4.z * ctxL[e4 * 4 + 2] + w4.w * ctxL[e4 * 4 + 3];
    }
    out[b * 1024 + h * NPH + o] = acc;
}

extern "C" void kernel_launch(void* const* d_in, const int* in_sizes, int n_in,
                              void* d_out, int out_size, void* d_ws, size_t ws_size,
                              hipStream_t stream) {
    const float* enc   = (const float*)d_in[0];
    const int*   elen  = (const int*)d_in[1];
    const float* dec   = (const float*)d_in[2];
    const float* Wenc  = (const float*)d_in[3];
    const float* benc  = (const float*)d_in[4];
    const float* Wdec  = (const float*)d_in[5];
    const float* bdec  = (const float*)d_in[6];
    const float* wattn = (const float*)d_in[7];
    const float* Wconv = (const float*)d_in[8];
    const float* Wloc  = (const float*)d_in[9];
    const float* bloc  = (const float*)d_in[10];
    const float* Wout  = (const float*)d_in[11];
    const float* bout  = (const float*)d_in[12];
    float* out = (float*)d_out;

    char* ws = (char*)d_ws;
    size_t off = 0;
    auto alloc = [&](size_t bytes) { size_t o = off; off += (bytes + 255) & ~(size_t)255; return o; };
    unsigned short* encbf  = (unsigned short*)(ws + alloc((size_t)NB * NT * NENC * 2));
    unsigned short* wencbf = (unsigned short*)(ws + alloc((size_t)NH * NENC * 2));
    float* wcum  = (float*)(ws + alloc((size_t)256 * 102 * 4));
    float* wlocT = (float*)(ws + alloc((size_t)NC * NH * 4));
    float* dech  = (float*)(ws + alloc((size_t)NHEAD * NB * NATTN * 4));
    float* addp  = (float*)(ws + alloc((size_t)NB * NPROF * NH * 4));
    float* scor  = (float*)(ws + alloc((size_t)NHEAD * NB * TP * 4));
    float* attn  = (float*)(ws + alloc((size_t)NHEAD * NB * NT * 4));
    float* ctxp  = (float*)(ws + alloc((size_t)4 * NHEAD * NB * NENC * 4));
    if (off > ws_size) return;  // insufficient workspace: bail (validation will flag it)

    hipFuncSetAttribute((const void*)k_gemm, hipFuncAttributeMaxDynamicSharedMemorySize, 131072);

    k_convert<<<2048, 256, 0, stream>>>(enc, encbf, NB * NT * NENC / 8);
    k_convert<<<64, 256, 0, stream>>>(Wenc, wencbf, NH * NENC / 8);
    k_wcum<<<1, 256, 0, stream>>>(Wconv, wcum);
    k_wlocT<<<64, 256, 0, stream>>>(Wloc, wlocT);
    k_dech<<<NHEAD * NB, 256, 0, stream>>>(dec, Wdec, bdec, dech);
    k_addprof<<<dim3((NPROF + 3) / 4, NB), 256, 0, stream>>>(wcum, dech, benc, bloc, wlocT, elen, addp);
    hipMemsetAsync(scor, 0, (size_t)NHEAD * NB * TP * 4, stream);
    k_gemm<<<2048, 512, 131072, stream>>>(encbf, wencbf, addp, wattn, elen, scor);
    k_softmax<<<NHEAD * NB, 256, 0, stream>>>(scor, elen, attn);
    k_attnw<<<dim3(8, NB), 256, 0, stream>>>(attn, out);
    k_ctx<<<dim3(4, 4, NB), 256, 0, stream>>>(enc, attn, elen, ctxp);
    k_out<<<dim3(NB, NHEAD), 256, 0, stream>>>(ctxp, Wout, bout, out);
}

// Round 6
// 774.609 us; speedup vs baseline: 1.4444x; 1.0094x over previous
//
#include <hip/hip_runtime.h>
#include <hip/hip_bf16.h>
#include <cstdint>

#define NB 32
#define NT 2000
#define TP 2048
#define NENC 1024
#define NDEC 1024
#define NATTN 512
#define NHEAD 4
#define NH 2048      // NHEAD*NATTN
#define NC 64
#define NKS 50
#define NKLEN 101
#define NPH 256
#define NPROF 101
#define NKT 32       // K tiles of 32 in the main GEMM

typedef __attribute__((ext_vector_type(8))) short bf16x8;
typedef __attribute__((ext_vector_type(4))) float f32x4;
typedef __attribute__((ext_vector_type(8))) unsigned short u16x8;

__device__ __forceinline__ void gload_lds16(const void* g, void* l) {
    __builtin_amdgcn_global_load_lds((__attribute__((address_space(1))) void*)(g),
                                     (__attribute__((address_space(3))) void*)(l), 16, 0, 0);
}

__device__ __forceinline__ unsigned short f2bf(float f) {
    unsigned u = __float_as_uint(f);
    return (unsigned short)((u + 0x7fffu + ((u >> 16) & 1u)) >> 16);
}

__device__ __forceinline__ int prof_of(int t, int len) {
    if (t < NKS) return t;
    if (t < len - NKS) return NKS;
    if (t < len) return NKS + 1 + (t - (len - NKS));
    return NKS;
}

__device__ __forceinline__ float4 f4add3(float4 a, float4 b, float4 c) {
    return make_float4(a.x + b.x + c.x, a.y + b.y + c.y, a.z + b.z + c.z, a.w + b.w + c.w);
}
__device__ __forceinline__ float4 f4fma(float s, float4 a, float4 acc) {
    return make_float4(fmaf(s, a.x, acc.x), fmaf(s, a.y, acc.y),
                       fmaf(s, a.z, acc.z), fmaf(s, a.w, acc.w));
}

// ---------------- f32 -> bf16 conversion (vectorized 8/thread) ----------------
__global__ void k_convert(const float* __restrict__ src, unsigned short* __restrict__ dst, int n8) {
    int stride = gridDim.x * blockDim.x;
    for (int i = blockIdx.x * blockDim.x + threadIdx.x; i < n8; i += stride) {
        const float4* s = (const float4*)(src) + (size_t)i * 2;
        float4 x = s[0], y = s[1];
        u16x8 o;
        o[0] = f2bf(x.x); o[1] = f2bf(x.y); o[2] = f2bf(x.z); o[3] = f2bf(x.w);
        o[4] = f2bf(y.x); o[5] = f2bf(y.y); o[6] = f2bf(y.z); o[7] = f2bf(y.w);
        *((u16x8*)dst + i) = o;
    }
}

// ---------------- prefix sums of Wconv rows: wcum[hc][0..101] ----------------
__global__ void k_wcum(const float* __restrict__ Wconv, float* __restrict__ wcum) {
    int hc = threadIdx.x;  // 256 rows
    float c = 0.f;
    wcum[hc * 102] = 0.f;
    for (int k = 0; k < NKLEN; ++k) {
        c += Wconv[hc * NKLEN + k];
        wcum[hc * 102 + k + 1] = c;
    }
}

// ---------------- WlocT[c][n] = Wloc[n][c] (512 KB, one-shot) ----------------
__global__ void k_wlocT(const float* __restrict__ Wloc, float* __restrict__ wlocT) {
    int c = blockIdx.x;  // 64
    for (int n = threadIdx.x; n < NH; n += 256)
        wlocT[c * NH + n] = Wloc[(size_t)n * NC + c];
}

// ---------------- dec_h[h][b][a] = Wdec[h,a,:].dec[b,:] + bdec ----------------
__global__ void k_dech(const float* __restrict__ dec, const float* __restrict__ Wdec,
                       const float* __restrict__ bdec, float* __restrict__ dech) {
    int h = blockIdx.x >> 5, b = blockIdx.x & 31;
    __shared__ float dl[NDEC];
    int tid = threadIdx.x;
    for (int r = 0; r < 4; ++r) dl[tid + r * 256] = dec[b * NDEC + tid + r * 256];
    __syncthreads();
    for (int a2 = 0; a2 < 2; ++a2) {
        int a = tid + a2 * 256;
        const float4* wr = (const float4*)&Wdec[((size_t)(h * NATTN + a)) * NDEC];
        float acc = 0.f;
        for (int e4 = 0; e4 < NDEC / 4; ++e4) {
            float4 w4 = wr[e4];
            acc += w4.x * dl[e4 * 4] + w4.y * dl[e4 * 4 + 1] + w4.z * dl[e4 * 4 + 2] + w4.w * dl[e4 * 4 + 3];
        }
        dech[(h * NB + b) * NATTN + a] = acc + bdec[h * NATTN + a];
    }
}

// ---- add[b][p][n] = dec_h + benc + bloc + WlocT^T . conv_profile(p) ----------
__global__ void k_addprof(const float* __restrict__ wcum, const float* __restrict__ dech,
                          const float* __restrict__ benc, const float* __restrict__ bloc,
                          const float* __restrict__ wlocT, const int* __restrict__ enc_len,
                          float* __restrict__ addp) {
    int p0 = blockIdx.x * 4, b = blockIdx.y;
    int len = enc_len[b];
    __shared__ float convp[4][256];
    int tid = threadIdx.x;
    float invl = 1.f / (float)len;
#pragma unroll
    for (int pp = 0; pp < 4; ++pp) {
        int p = min(p0 + pp, NPROF - 1);
        int kmin, kmax;
        if (p < NKS)       { kmin = NKS - p; kmax = min(NKLEN, len - p + NKS); }
        else if (p == NKS) { kmin = 0;       kmax = NKLEN; }
        else               { kmin = 0;       kmax = 151 - p; }
        if (kmax < kmin) kmax = kmin;
        convp[pp][tid] = (wcum[tid * 102 + kmax] - wcum[tid * 102 + kmin]) * invl;
    }
    __syncthreads();
    int h0 = tid >> 7, h1 = 2 + h0;
    int n40 = tid, n41 = 256 + tid;   // float4 indices into the 2048-wide n dim
    const float4* dech4 = (const float4*)dech;
    const float4* benc4 = (const float4*)benc;
    const float4* bloc4 = (const float4*)bloc;
    float4 base0 = f4add3(dech4[(h0 * NB + b) * 128 + (tid & 127)], benc4[n40], bloc4[n40]);
    float4 base1 = f4add3(dech4[(h1 * NB + b) * 128 + (tid & 127)], benc4[n41], bloc4[n41]);
    float4 acc[4][2];
#pragma unroll
    for (int pp = 0; pp < 4; ++pp) { acc[pp][0] = base0; acc[pp][1] = base1; }
    const float4* wT4 = (const float4*)wlocT;
#pragma unroll 4
    for (int c = 0; c < NC; ++c) {
        float4 w0 = wT4[c * 512 + n40];
        float4 w1 = wT4[c * 512 + n41];
#pragma unroll
        for (int pp = 0; pp < 4; ++pp) {
            acc[pp][0] = f4fma(convp[pp][h0 * 64 + c], w0, acc[pp][0]);
            acc[pp][1] = f4fma(convp[pp][h1 * 64 + c], w1, acc[pp][1]);
        }
    }
    float4* addp4 = (float4*)addp;
#pragma unroll
    for (int pp = 0; pp < 4; ++pp) {
        int p = p0 + pp;
        if (p < NPROF) {
            addp4[((size_t)(b * NPROF + p)) * 512 + n40] = acc[pp][0];
            addp4[((size_t)(b * NPROF + p)) * 512 + n41] = acc[pp][1];
        }
    }
}

// ---------------- main fused GEMM + tanh + wattn-reduce -> scores -------------
// 256x256 tile, BK=32, 8 waves (2x4), 4-deep LDS ring, m201-style phases.
// Cross-wave visibility rule: any LDS read of rows staged by OTHER waves must
// sit after {all waves' vmcnt retiring that buffer} + {a barrier}.
// PHA(kt): {read b0,b1(buf kt) | stage A(kt+3) | BAR | lgkm0 | 16 MFMA | BAR}
// PHB(kt): {vmcnt (retires buf kt+1) | read b2,b3(buf kt) | stage B(kt+3) |
//           BAR | lgkm0 | prefetch A(kt+1) frags (now safe) | 16 MFMA | BAR}
__global__ __launch_bounds__(512, 2) void k_gemm(
        const unsigned short* __restrict__ encbf, const unsigned short* __restrict__ wencbf,
        const float* __restrict__ addp, const float* __restrict__ wattn,
        const int* __restrict__ enc_len, float* __restrict__ scores) {
    extern __shared__ char smem[];
    int bid = blockIdx.x;
    int L = (bid & 7) * 256 + (bid >> 3);   // bijective XCD-chunk swizzle (2048%8==0)
    int bx = L & 7, by = (L >> 3) & 7, b = L >> 6;
    int n0 = bx * 256, t0 = by * 256;
    int len = enc_len[b];
    if (t0 >= len) return;  // fully-masked tile
    int tid = threadIdx.x, lane = tid & 63, w = tid >> 6;
    int wr = w >> 2, wc = w & 3;
    int ro = lane & 15, g4 = lane >> 4;

    // staging geometry: wave w stages rows w*32..w*32+31 (2 gloads of 1KB each)
    int srow = w * 32 + (lane >> 2);
    int csrc = ((lane & 3) ^ ((lane >> 3) & 3)) * 8;  // pre-swizzled k-chunk (elements)
    const unsigned short* Asrc0 = encbf + (size_t)b * NT * NENC + (size_t)(t0 + srow) * NENC + csrc;
    const unsigned short* Bsrc0 = wencbf + (size_t)(n0 + srow) * NENC + csrc;
    char* dA = smem + w * 2048;
    char* dB = smem + 16384 + w * 2048;

    auto STAGE_A = [&](int kt) {
        char* d = dA + ((kt & 3) << 15);
        const unsigned short* s = Asrc0 + kt * 32;
        gload_lds16(s, d);
        gload_lds16(s + 16 * NENC, d + 1024);
    };
    auto STAGE_B = [&](int kt) {
        char* d = dB + ((kt & 3) << 15);
        const unsigned short* s = Bsrc0 + kt * 32;
        gload_lds16(s, d);
        gload_lds16(s + 16 * NENC, d + 1024);
    };

    f32x4 acc[8][4] = {};
    bf16x8 aE[8], aO[8];
    int swb = (g4 ^ ((ro >> 1) & 3)) * 16;               // swizzled chunk byte on read
    int rdA = (wr * 128 + ro) * 64 + swb;                 // + m*1024 + q*32768
    int rdB = 16384 + (wc * 64 + ro) * 64 + swb;          // + n*1024 + q*32768

    STAGE_A(0); STAGE_B(0); STAGE_A(1); STAGE_B(1); STAGE_A(2); STAGE_B(2);
    asm volatile("s_waitcnt vmcnt(8)" ::: "memory");   // A0,B0 retired (this wave)
    asm volatile("s_barrier" ::: "memory");            // ...and all other waves
#pragma unroll
    for (int m = 0; m < 8; ++m) aE[m] = *(const bf16x8*)(smem + rdA + m * 1024);

#define BAR asm volatile("s_barrier" ::: "memory")
#define LGKM0 { asm volatile("s_waitcnt lgkmcnt(0)" ::: "memory"); __builtin_amdgcn_sched_barrier(0); }
#define PHA(KT, AR, ST) \
    { const char* Aq = smem + (((KT) & 3) << 15); \
      bf16x8 b0 = *(const bf16x8*)(Aq + rdB); \
      bf16x8 b1 = *(const bf16x8*)(Aq + rdB + 1024); \
      if (ST) STAGE_A((KT) + 3); \
      BAR; LGKM0; \
      __builtin_amdgcn_s_setprio(1); \
      _Pragma("unroll") \
      for (int m = 0; m < 8; ++m) { \
          acc[m][0] = __builtin_amdgcn_mfma_f32_16x16x32_bf16(AR[m], b0, acc[m][0], 0, 0, 0); \
          acc[m][1] = __builtin_amdgcn_mfma_f32_16x16x32_bf16(AR[m], b1, acc[m][1], 0, 0, 0); } \
      __builtin_amdgcn_s_setprio(0); \
      BAR; }
#define PHB(KT, AR, AN, ST, VM, PF) \
    { asm volatile("s_waitcnt vmcnt(" #VM ")" ::: "memory"); \
      const char* Aq = smem + (((KT) & 3) << 15); \
      const char* Aq1 = smem + ((((KT) + 1) & 3) << 15); \
      bf16x8 b2 = *(const bf16x8*)(Aq + rdB + 2048); \
      bf16x8 b3 = *(const bf16x8*)(Aq + rdB + 3072); \
      if (ST) STAGE_B((KT) + 3); \
      BAR; LGKM0; \
      if (PF) { _Pragma("unroll") \
          for (int m = 0; m < 8; ++m) AN[m] = *(const bf16x8*)(Aq1 + rdA + m * 1024); } \
      __builtin_amdgcn_s_setprio(1); \
      _Pragma("unroll") \
      for (int m = 0; m < 8; ++m) { \
          acc[m][2] = __builtin_amdgcn_mfma_f32_16x16x32_bf16(AR[m], b2, acc[m][2], 0, 0, 0); \
          acc[m][3] = __builtin_amdgcn_mfma_f32_16x16x32_bf16(AR[m], b3, acc[m][3], 0, 0, 0); } \
      __builtin_amdgcn_s_setprio(0); \
      BAR; }

#pragma unroll 1
    for (int p = 0; p < 14; ++p) {
        int k0 = 2 * p, k1 = 2 * p + 1;
        PHA(k0, aE, 1)
        PHB(k0, aE, aO, 1, 6, 1)
        PHA(k1, aO, 1)
        PHB(k1, aO, aE, 1, 6, 1)
    }
    PHA(28, aE, 1) PHB(28, aE, aO, 1, 6, 1)
    PHA(29, aO, 0) PHB(29, aO, aE, 0, 4, 1)
    PHA(30, aE, 0) PHB(30, aE, aO, 0, 0, 1)
    PHA(31, aO, 0) PHB(31, aO, aE, 0, 0, 0)
#undef PHA
#undef PHB
#undef LGKM0
#undef BAR

    __builtin_amdgcn_sched_barrier(0);
    // epilogue: tanh(acc+add)*wattn, 16-lane reduce over n, atomicAdd to scores
    int h = n0 >> 9;
    float wat[4];
#pragma unroll
    for (int n = 0; n < 4; ++n) wat[n] = wattn[n0 + wc * 64 + n * 16 + ro];
    const float* addb = addp + (size_t)b * NPROF * NH + n0 + wc * 64 + ro;
    float* sr = scores + ((size_t)(h * NB + b)) * TP;
#pragma unroll
    for (int m = 0; m < 8; ++m) {
#pragma unroll
        for (int e = 0; e < 4; ++e) {
            int t = t0 + wr * 128 + m * 16 + g4 * 4 + e;
            int tc = t < NT ? t : NT - 1;
            const float* arow = addb + (size_t)prof_of(tc, len) * NH;
            float s = 0.f;
#pragma unroll
            for (int n = 0; n < 4; ++n) {
                float v = acc[m][n][e] + arow[n * 16];
                v = fminf(fmaxf(v, -15.f), 15.f);
                float e2 = __expf(2.f * v);
                s += ((e2 - 1.f) / (e2 + 1.f)) * wat[n];
            }
            s += __shfl_xor(s, 1); s += __shfl_xor(s, 2);
            s += __shfl_xor(s, 4); s += __shfl_xor(s, 8);
            if (ro == 0) atomicAdd(&sr[t], s);
        }
    }
}

// ---------------- masked softmax over t per (h,b) -> attn ---------------------
__global__ void k_softmax(const float* __restrict__ scores, const int* __restrict__ enc_len,
                          float* __restrict__ attn) {
    int h = blockIdx.x >> 5, b = blockIdx.x & 31;
    int len = enc_len[b];
    int tid = threadIdx.x;
    const float* row = scores + ((size_t)(h * NB + b)) * TP;
    __shared__ float red[4];
    float m = -1e30f;
    for (int t = tid; t < len; t += 256) m = fmaxf(m, row[t]);
    for (int d = 32; d; d >>= 1) m = fmaxf(m, __shfl_xor(m, d));
    if ((tid & 63) == 0) red[tid >> 6] = m;
    __syncthreads();
    m = fmaxf(fmaxf(red[0], red[1]), fmaxf(red[2], red[3]));
    __syncthreads();
    float z = 0.f;
    for (int t = tid; t < len; t += 256) z += __expf(row[t] - m);
    for (int d = 32; d; d >>= 1) z += __shfl_xor(z, d);
    if ((tid & 63) == 0) red[tid >> 6] = z;
    __syncthreads();
    z = red[0] + red[1] + red[2] + red[3];
    float inv = 1.f / z;
    for (int t = tid; t < NT; t += 256) {
        float av = (t < len) ? __expf(row[t] - m) * inv : 0.f;
        attn[((size_t)(h * NB + b)) * NT + t] = av;
    }
}

// ---------------- attn_weight = mean over heads ------------------------------
__global__ void k_attnw(const float* __restrict__ attn, float* __restrict__ out) {
    int b = blockIdx.y;
    int t = blockIdx.x * 256 + threadIdx.x;
    if (t < NT) {
        float s = 0.f;
        for (int h = 0; h < NHEAD; ++h) s += attn[((size_t)(h * NB + b)) * NT + t];
        out[NB * 1024 + b * NT + t] = 0.25f * s;
    }
}

// ---------------- ctx partials: [ts][h][b][e] --------------------------------
__global__ void k_ctx(const float* __restrict__ enc, const float* __restrict__ attn,
                      const int* __restrict__ enc_len, float* __restrict__ ctxp) {
    int ec = blockIdx.x, ts = blockIdx.y, b = blockIdx.z;
    int tid = threadIdx.x;
    __shared__ float attnL[NHEAD][500];
    int t0 = ts * 500;
    for (int i = tid; i < NHEAD * 500; i += 256) {
        int hh = i / 500, tt = i - hh * 500;
        attnL[hh][tt] = attn[((size_t)(hh * NB + b)) * NT + t0 + tt];
    }
    __syncthreads();
    int len = enc_len[b];
    int t1 = min(t0 + 500, len);
    int e = ec * 256 + tid;
    float a0 = 0.f, a1 = 0.f, a2 = 0.f, a3 = 0.f;
    for (int t = t0; t < t1; ++t) {
        float ev = enc[((size_t)b * NT + t) * NENC + e];
        int tt = t - t0;
        a0 += attnL[0][tt] * ev; a1 += attnL[1][tt] * ev;
        a2 += attnL[2][tt] * ev; a3 += attnL[3][tt] * ev;
    }
    ctxp[(((size_t)ts * NHEAD + 0) * NB + b) * NENC + e] = a0;
    ctxp[(((size_t)ts * NHEAD + 1) * NB + b) * NENC + e] = a1;
    ctxp[(((size_t)ts * NHEAD + 2) * NB + b) * NENC + e] = a2;
    ctxp[(((size_t)ts * NHEAD + 3) * NB + b) * NENC + e] = a3;
}

// ---------------- out[h][b][o] = Wout[h,o,:].ctx + bout ----------------------
__global__ void k_out(const float* __restrict__ ctxp, const float* __restrict__ Wout,
                      const float* __restrict__ bout, float* __restrict__ out) {
    int b = blockIdx.x, h = blockIdx.y;
    int tid = threadIdx.x;
    __shared__ float ctxL[NENC];
    for (int r = 0; r < 4; ++r) {
        int e = tid + r * 256;
        float s = 0.f;
        for (int s4 = 0; s4 < 4; ++s4) s += ctxp[(((size_t)s4 * NHEAD + h) * NB + b) * NENC + e];
        ctxL[e] = s;
    }
    __syncthreads();
    int o = tid;
    float acc = bout[h * NPH + o];
    const float4* wrow = (const float4*)&Wout[((size_t)(h * NPH + o)) * NENC];
    for (int e4 = 0; e4 < NENC / 4; ++e4) {
        float4 w4 = wrow[e4];
        acc += w4.x * ctxL[e4 * 4] + w4.y * ctxL[e4 * 4 + 1] + w4.z * ctxL[e4 * 4 + 2] + w4.w * ctxL[e4 * 4 + 3];
    }
    out[b * 1024 + h * NPH + o] = acc;
}

extern "C" void kernel_launch(void* const* d_in, const int* in_sizes, int n_in,
                              void* d_out, int out_size, void* d_ws, size_t ws_size,
                              hipStream_t stream) {
    const float* enc   = (const float*)d_in[0];
    const int*   elen  = (const int*)d_in[1];
    const float* dec   = (const float*)d_in[2];
    const float* Wenc  = (const float*)d_in[3];
    const float* benc  = (const float*)d_in[4];
    const float* Wdec  = (const float*)d_in[5];
    const float* bdec  = (const float*)d_in[6];
    const float* wattn = (const float*)d_in[7];
    const float* Wconv = (const float*)d_in[8];
    const float* Wloc  = (const float*)d_in[9];
    const float* bloc  = (const float*)d_in[10];
    const float* Wout  = (const float*)d_in[11];
    const float* bout  = (const float*)d_in[12];
    float* out = (float*)d_out;

    char* ws = (char*)d_ws;
    size_t off = 0;
    auto alloc = [&](size_t bytes) { size_t o = off; off += (bytes + 255) & ~(size_t)255; return o; };
    unsigned short* encbf  = (unsigned short*)(ws + alloc((size_t)NB * NT * NENC * 2));
    unsigned short* wencbf = (unsigned short*)(ws + alloc((size_t)NH * NENC * 2));
    float* wcum  = (float*)(ws + alloc((size_t)256 * 102 * 4));
    float* wlocT = (float*)(ws + alloc((size_t)NC * NH * 4));
    float* dech  = (float*)(ws + alloc((size_t)NHEAD * NB * NATTN * 4));
    float* addp  = (float*)(ws + alloc((size_t)NB * NPROF * NH * 4));
    float* scor  = (float*)(ws + alloc((size_t)NHEAD * NB * TP * 4));
    float* attn  = (float*)(ws + alloc((size_t)NHEAD * NB * NT * 4));
    float* ctxp  = (float*)(ws + alloc((size_t)4 * NHEAD * NB * NENC * 4));
    if (off > ws_size) return;  // insufficient workspace: bail (validation will flag it)

    hipFuncSetAttribute((const void*)k_gemm, hipFuncAttributeMaxDynamicSharedMemorySize, 131072);

    k_convert<<<2048, 256, 0, stream>>>(enc, encbf, NB * NT * NENC / 8);
    k_convert<<<64, 256, 0, stream>>>(Wenc, wencbf, NH * NENC / 8);
    k_wcum<<<1, 256, 0, stream>>>(Wconv, wcum);
    k_wlocT<<<64, 256, 0, stream>>>(Wloc, wlocT);
    k_dech<<<NHEAD * NB, 256, 0, stream>>>(dec, Wdec, bdec, dech);
    k_addprof<<<dim3((NPROF + 3) / 4, NB), 256, 0, stream>>>(wcum, dech, benc, bloc, wlocT, elen, addp);
    hipMemsetAsync(scor, 0, (size_t)NHEAD * NB * TP * 4, stream);
    k_gemm<<<2048, 512, 131072, stream>>>(encbf, wencbf, addp, wattn, elen, scor);
    k_softmax<<<NHEAD * NB, 256, 0, stream>>>(scor, elen, attn);
    k_attnw<<<dim3(8, NB), 256, 0, stream>>>(attn, out);
    k_ctx<<<dim3(4, 4, NB), 256, 0, stream>>>(enc, attn, elen, ctxp);
    k_out<<<dim3(NB, NHEAD), 256, 0, stream>>>(ctxp, Wout, bout, out);
}